// Round 13
// baseline (204.466 us; speedup 1.0000x reference)
//
#include <hip/hip_runtime.h>
#include <hip/hip_bf16.h>
#include <math.h>

#define BB 4
#define LL 8192
#define DD 512
#define HH 8
#define MM (BB*LL)      // 32768
#define NQKV 1536
#define CH 16           // K-chunks for kv partial reduction (Kc = 512)

typedef __attribute__((ext_vector_type(4))) float f32x4;
typedef __attribute__((ext_vector_type(8))) short s16x8;
typedef __attribute__((ext_vector_type(4))) short s16x4;

__device__ __forceinline__ float bf2f(short u) {
  union { unsigned int i; float f; } c;
  c.i = ((unsigned int)(unsigned short)u) << 16;
  return c.f;
}
__device__ __forceinline__ short f2bf(float f) {
  union { float f; unsigned int i; } c; c.f = f;
  unsigned int r = c.i + 0x7FFFu + ((c.i >> 16) & 1u);
  return (short)(r >> 16);
}

__device__ __forceinline__ void gload16(const void* g, void* l) {
  __builtin_amdgcn_global_load_lds(
      (const __attribute__((address_space(1))) void*)(g),
      (__attribute__((address_space(3))) void*)(l), 16, 0, 0);
}

// ---------------- conversion kernels ----------------
__global__ void conv_bf16(const float* __restrict__ in, short* __restrict__ out, int n) {
  int i = (blockIdx.x * blockDim.x + threadIdx.x) * 8;
  if (i < n) {
    float4 v0 = *reinterpret_cast<const float4*>(in + i);
    float4 v1 = *reinterpret_cast<const float4*>(in + i + 4);
    s16x8 o;
    o[0] = f2bf(v0.x); o[1] = f2bf(v0.y); o[2] = f2bf(v0.z); o[3] = f2bf(v0.w);
    o[4] = f2bf(v1.x); o[5] = f2bf(v1.y); o[6] = f2bf(v1.z); o[7] = f2bf(v1.w);
    *reinterpret_cast<s16x8*>(out + i) = o;
  }
}

// w[K][N] (row-major) -> wt[N][K] bf16
__global__ void conv_wt(const float* __restrict__ w, short* __restrict__ wt, int K, int N) {
  int idx = blockIdx.x * blockDim.x + threadIdx.x;
  if (idx < K * N) {
    int n = idx / K, k = idx - n * K;
    wt[idx] = f2bf(w[(size_t)k * N + n]);
  }
}

// ---------------- bf16 MFMA GEMM, qkv = x @ wqkv^T + bias ----------------
// 256x128 tile, BK=64, 8 waves (4M x 2N).  A fragments DIRECT FROM GLOBAL
// (L2-hot via m-major XCD chunking; n-wave pairs share rows via L1).  Only B
// staged in LDS: double-buffered 2x16KB, one barrier + vmcnt(0) per K-tile.
// This halves LDS traffic vs staging both (r12 was LDS-BW-bound at 27% MfmaUtil).
// B staging swizzle: row r, 16B-unit u stored at (u ^ (r&7)), pre-swizzled source.
// q cols -> phi + row-major q_b[M][512];
// k cols -> phi + per-head transpose kt[head][dh][8192];
// v cols -> per-head transpose vt[head][m][8192].
__global__ __launch_bounds__(512, 4)
void gemm_bt(const short* __restrict__ A, const short* __restrict__ BT,
             const float* __restrict__ bias, void* __restrict__ Cout,
             short* __restrict__ ktb, short* __restrict__ vtb)
{
  constexpr int KD = 512;
  __shared__ __align__(16) char lds[65536];   // B slots 2x16KB @0; epilogue reuses 64KB

  const int tid = threadIdx.x;
  const int wv = tid >> 6, lane = tid & 63;
  const int wm = wv >> 1, wn = wv & 1;        // 4 m-waves x 2 n-waves
  const int fr = lane & 15, fq = lane >> 4;

  // m-major XCD chunking: each XCD owns a contiguous m-stripe
  const int gx = gridDim.x;                   // # m-blocks
  const int gy = gridDim.y;                   // # n-blocks
  const int d = blockIdx.y * gx + blockIdx.x;
  const int nwg = gx * gy;
  const int lin = (d & 7) * (nwg >> 3) + (d >> 3);
  const int m0 = (lin / gy) * 256, n0 = (lin % gy) * 128;

  // B staging: round covers rows (tid>>3) + round*64; LDS unit tid&7 holds
  // global unit (tid&7)^(row&7)
  const int srow = tid >> 3;
  const int sunit = (tid & 7) ^ (srow & 7);
  const short* Bg = BT + (size_t)(n0 + srow) * KD + sunit * 8;
  char* ldsw = lds + wv * 1024;               // + lane*16 implicit in gload_lds

  // A direct-global fragment base: row m0 + wm*64 + i*16 + fr, col k0+kk*32+fq*8
  const short* Ab = A + (size_t)(m0 + wm * 64 + fr) * KD + fq * 8;

  f32x4 acc[4][4] = {};

  // prologue: stage B(0) into slot 0
  gload16(Bg,                   ldsw);
  gload16(Bg + (size_t)64 * KD, ldsw + 8192);

  for (int t = 0; t < 8; ++t) {
    asm volatile("s_waitcnt vmcnt(0)" ::: "memory");   // B(t) landed
    __syncthreads();                                   // slot (t+1)&1 readers done
    const int slot = (t & 1) * 16384;
    if (t < 7) {
      const int k1 = (t + 1) * 64;
      const int ns = ((t + 1) & 1) * 16384;
      gload16(Bg + k1,                   lds + ns + wv * 1024);
      gload16(Bg + (size_t)64 * KD + k1, lds + ns + 8192 + wv * 1024);
    }
    const int k0 = t * 64;
#pragma unroll
    for (int kk = 0; kk < 2; ++kk) {
      s16x8 af[4], bfg[4];
#pragma unroll
      for (int i = 0; i < 4; ++i)
        af[i] = *(const s16x8*)(Ab + (size_t)(i * 16) * KD + k0 + kk * 32);
#pragma unroll
      for (int j = 0; j < 4; ++j) {
        const int rb = wn * 64 + j * 16 + fr;
        const int ub = (kk * 4 + fq) ^ (rb & 7);
        bfg[j] = *(const s16x8*)(lds + slot + rb * 128 + ub * 16);
      }
#pragma unroll
      for (int i = 0; i < 4; ++i)
#pragma unroll
        for (int j = 0; j < 4; ++j)
          acc[i][j] = __builtin_amdgcn_mfma_f32_16x16x32_bf16(af[i], bfg[j], acc[i][j], 0, 0, 0);
    }
  }
  __syncthreads();   // protect LDS before epilogue reuse

  // ---- epilogue (identical to r12) ----
  if (n0 < 512) {
    // q: phi + row-major bf16 to Cout (q_b), stride 512
    short* scr = (short*)lds;   // 256x128
#pragma unroll
    for (int j = 0; j < 4; ++j) {
      const int col = wn * 64 + j * 16 + fr;
      const float bv = bias[n0 + col];
#pragma unroll
      for (int i = 0; i < 4; ++i) {
        const int row = wm * 64 + i * 16 + fq * 4;
#pragma unroll
        for (int r = 0; r < 4; ++r) {
          float v = acc[i][j][r] + bv;
          v = (v > 0.f) ? (v + 1.f) : __expf(v);   // phi = elu+1
          scr[(row + r) * 128 + col] = f2bf(v);
        }
      }
    }
    __syncthreads();
#pragma unroll
    for (int p = 0; p < 8; ++p) {
      const int off = p * 8192 + tid * 16;          // bytes
      const int row = off >> 8, colb = off & 255;   // 256B per row
      s16x8 v = *(const s16x8*)(lds + off);
      *(s16x8*)((short*)Cout + (size_t)(m0 + row) * 512 + n0 + (colb >> 1)) = v;
    }
  } else {
    // k/v: (phi for k) + per-head transposed write via scr_t[col][l]
    const bool do_phi = (n0 < 1024);
    short* tdst = do_phi ? ktb : vtb;
    const int f0 = n0 - (do_phi ? 512 : 1024);
#pragma unroll
    for (int j = 0; j < 4; ++j) {
      const int col = wn * 64 + j * 16 + fr;
      const float bv = bias[n0 + col];
      const int cx = col & 31;
#pragma unroll
      for (int i = 0; i < 4; ++i) {
        const int l = wm * 64 + i * 16 + fq * 4;
        s16x4 pk;
#pragma unroll
        for (int r = 0; r < 4; ++r) {
          float v = acc[i][j][r] + bv;
          if (do_phi) v = (v > 0.f) ? (v + 1.f) : __expf(v);
          pk[r] = f2bf(v);
        }
        *(s16x4*)(lds + col * 512 + (((l >> 3) ^ cx) * 16) + (l & 7) * 2) = pk;
      }
    }
    __syncthreads();
#pragma unroll
    for (int p = 0; p < 8; ++p) {
      const int g = p * 512 + tid;
      const int col = g >> 5, up = g & 31;
      const int u = up ^ (col & 31);
      s16x8 v = *(const s16x8*)(lds + col * 512 + up * 16);
      const int f = f0 + col;
      const int hb = ((m0 >> 13) << 3) + (f >> 6);
      short* dst = tdst + ((size_t)hb * 64 + (f & 63)) * 8192 + (m0 & 8191) + u * 8;
      *(s16x8*)dst = v;
    }
  }
}

// ---------------- kv partials via MFMA ----------------
__global__ __launch_bounds__(256, 4)
void kv_mfma(const short* __restrict__ kt, const short* __restrict__ vt,
             float* __restrict__ pkv, float* __restrict__ pks)
{
  const int hb = blockIdx.x, c = blockIdx.y;
  const int tid = threadIdx.x, wv = tid >> 6, lane = tid & 63;
  const int fr = lane & 15, fq = lane >> 4;
  const size_t base = (size_t)hb * 64 * 8192;
  const int l0 = c * 512;
  const short* vrow = vt + base + (size_t)fr * 8192 + l0 + fq * 8;
  const short* krow = kt + base + (size_t)(wv * 16 + fr) * 8192 + l0 + fq * 8;

  s16x8 ones;
#pragma unroll
  for (int j = 0; j < 8; ++j) ones[j] = (short)0x3F80;   // bf16 1.0

  f32x4 acc[4] = {};
  f32x4 accd = {};
#pragma unroll
  for (int ks = 0; ks < 16; ++ks) {
    s16x8 bfr = *(const s16x8*)(krow + ks * 32);
    accd = __builtin_amdgcn_mfma_f32_16x16x32_bf16(ones, bfr, accd, 0, 0, 0);
#pragma unroll
    for (int i = 0; i < 4; ++i) {
      s16x8 af = *(const s16x8*)(vrow + (size_t)(i * 16) * 8192 + ks * 32);
      acc[i] = __builtin_amdgcn_mfma_f32_16x16x32_bf16(af, bfr, acc[i], 0, 0, 0);
    }
  }
  float* o = pkv + ((size_t)hb * CH + c) * 4096;
#pragma unroll
  for (int i = 0; i < 4; ++i)
#pragma unroll
    for (int r = 0; r < 4; ++r)
      o[(i * 16 + fq * 4 + r) * 64 + wv * 16 + fr] = acc[i][r];
  if (fq == 0)
    pks[((size_t)hb * CH + c) * 64 + wv * 16 + fr] = accd[0];
}

// reduce partials -> bf16 kv_b [head][m][d], bf16 ksum_b [head][d] (with +1e-6)
__global__ void kv_reduce(const float* __restrict__ pkv, const float* __restrict__ pks,
                          short* __restrict__ kv_b, short* __restrict__ ksum_b)
{
  const int idx = blockIdx.x * 256 + threadIdx.x;   // head*4096 + m*64 + d
  const int head = idx >> 12, md = idx & 4095;
  float s = 0.f;
  for (int i = 0; i < CH; ++i) s += pkv[((size_t)head * CH + i) * 4096 + md];
  kv_b[idx] = f2bf(s);
  if (md < 64) {
    float t = 0.f;
    for (int i = 0; i < CH; ++i) t += pks[((size_t)head * CH + i) * 64 + md];
    ksum_b[head * 64 + md] = f2bf(t + 1e-6f);
  }
}

// ---------------- fused attn + output GEMM (r12-proven) ----------------
__global__ __launch_bounds__(256, 2)
void attn_out(const short* __restrict__ q_b, const short* __restrict__ kv_b,
              const short* __restrict__ ksum_b, const short* __restrict__ wo_t,
              const float* __restrict__ b_out, float* __restrict__ out)
{
  __shared__ __align__(16) char lds[73728];   // At 8KB @0 | Ws 64KB @8192
  const int tid = threadIdx.x;
  const int wv = tid >> 6, lane = tid & 63;
  const int fr = lane & 15, fq = lane >> 4;
  const int l0 = blockIdx.x * 64;
  const int bb = l0 >> 13;                    // batch index

  const int srow = tid >> 3;
  const int sunit = (tid & 7) ^ (srow & 7);
  const short* Wg = wo_t + (size_t)srow * 512 + sunit * 8;
  char* ldsw = lds + 8192 + wv * 1024;        // + lane*16 implicit in gload_lds

  f32x4 acc[4][8] = {};

  for (int h = 0; h < 8; ++h) {
#pragma unroll
    for (int i = 0; i < 16; ++i)
      gload16(Wg + (size_t)(i * 32) * 512 + h * 64, ldsw + i * 4096);

    // ---- phase A: attn for head h, this wave's 16-row slab ----
    {
      const int hb = bb * 8 + h;
      const short* kvp = kv_b + (size_t)hb * 4096;
      const short* ksp = ksum_b + hb * 64;
      const short* qb = q_b + (size_t)(l0 + wv * 16) * 512 + h * 64;
      f32x4 accn[4] = {};
      f32x4 accd = {};
#pragma unroll
      for (int kk = 0; kk < 2; ++kk) {
        s16x8 a = *(const s16x8*)(qb + (size_t)fr * 512 + kk * 32 + fq * 8);
        s16x8 bden = *(const s16x8*)(ksp + kk * 32 + fq * 8);
        accd = __builtin_amdgcn_mfma_f32_16x16x32_bf16(a, bden, accd, 0, 0, 0);
#pragma unroll
        for (int j = 0; j < 4; ++j) {
          s16x8 bfr = *(const s16x8*)(kvp + (j * 16 + fr) * 64 + kk * 32 + fq * 8);
          accn[j] = __builtin_amdgcn_mfma_f32_16x16x32_bf16(a, bfr, accn[j], 0, 0, 0);
        }
      }
#pragma unroll
      for (int r = 0; r < 4; ++r) {
        const int row = wv * 16 + fq * 4 + r;
        const float dinv = 1.0f / accd[r];
#pragma unroll
        for (int j = 0; j < 4; ++j) {
          const int col = j * 16 + fr;
          *(short*)(lds + row * 128 + (((col >> 3) ^ (row & 7)) << 4) + ((col & 7) << 1))
              = f2bf(accn[j][r] * dinv);
        }
      }
    }
    __syncthreads();   // At ready + Ws landed

    // ---- phase B: acc += At @ Ws^T over this chunk's K=64 ----
#pragma unroll
    for (int kk = 0; kk < 2; ++kk) {
      s16x8 af[4];
#pragma unroll
      for (int i = 0; i < 4; ++i) {
        const int row = i * 16 + fr;
        const int u = (kk * 4 + fq) ^ (row & 7);
        af[i] = *(const s16x8*)(lds + row * 128 + u * 16);
      }
#pragma unroll
      for (int j = 0; j < 8; ++j) {
        const int n = wv * 128 + j * 16 + fr;
        const int u = (kk * 4 + fq) ^ (n & 7);
        s16x8 bw = *(const s16x8*)(lds + 8192 + n * 128 + u * 16);
#pragma unroll
        for (int i = 0; i < 4; ++i)
          acc[i][j] = __builtin_amdgcn_mfma_f32_16x16x32_bf16(af[i], bw, acc[i][j], 0, 0, 0);
      }
    }
    __syncthreads();   // protect At/Ws for next chunk
  }

  // ---- epilogue: 2 passes of 32 rows through 64KB fp32 scratch ----
  float* scrf = (float*)lds;
#pragma unroll
  for (int p = 0; p < 2; ++p) {
#pragma unroll
    for (int ii = 0; ii < 2; ++ii) {
      const int i = 2 * p + ii;
#pragma unroll
      for (int j = 0; j < 8; ++j) {
        const int col = wv * 128 + j * 16 + fr;
        const float bv = b_out[col];
#pragma unroll
        for (int r = 0; r < 4; ++r)
          scrf[(ii * 16 + fq * 4 + r) * 512 + col] = acc[i][j][r] + bv;
      }
    }
    __syncthreads();
#pragma unroll
    for (int pp = 0; pp < 16; ++pp) {
      const int off = pp * 4096 + tid * 16;
      const int row = off >> 11, colb = off & 2047;   // 2KB per row (512 fp32)
      float4 v = *(const float4*)(lds + off);
      *(float4*)(out + (size_t)(l0 + p * 32 + row) * 512 + (colb >> 2)) = v;
    }
    __syncthreads();
  }
}

// ---------------- launch ----------------
extern "C" void kernel_launch(void* const* d_in, const int* in_sizes, int n_in,
                              void* d_out, int out_size, void* d_ws, size_t ws_size,
                              hipStream_t stream)
{
  const float* x     = (const float*)d_in[0];
  const float* w_qkv = (const float*)d_in[1];
  const float* b_qkv = (const float*)d_in[2];
  const float* w_out = (const float*)d_in[3];
  const float* b_out = (const float*)d_in[4];

  char* ws = (char*)d_ws;
  size_t off = 0;
  short* x_b   = (short*)(ws + off); off += (size_t)MM * DD * 2;        // 32 MB
  short* wq_t  = (short*)(ws + off); off += (size_t)NQKV * DD * 2;      // 1.5 MB
  short* wo_t  = (short*)(ws + off); off += (size_t)DD * DD * 2;        // 0.5 MB
  short* q_b   = (short*)(ws + off); off += (size_t)MM * DD * 2;        // 32 MB
  short* kt    = (short*)(ws + off); off += (size_t)32 * 64 * LL * 2;   // 32 MB
  short* vt    = (short*)(ws + off); off += (size_t)32 * 64 * LL * 2;   // 32 MB
  float* pkv   = (float*)(ws + off); off += (size_t)32 * CH * 4096 * 4; // 8 MB
  float* pks   = (float*)(ws + off); off += (size_t)32 * CH * 64 * 4;   // 0.13 MB
  short* kv_b  = (short*)(ws + off); off += (size_t)32 * 4096 * 2;      // 0.25 MB
  short* ksum_b= (short*)(ws + off); off += (size_t)32 * 64 * 2;        // 4 KB

  conv_bf16<<<dim3(MM * DD / 8 / 256), dim3(256), 0, stream>>>(x, x_b, MM * DD);
  conv_wt<<<dim3((DD * NQKV + 255) / 256), dim3(256), 0, stream>>>(w_qkv, wq_t, DD, NQKV);
  conv_wt<<<dim3((DD * DD + 255) / 256), dim3(256), 0, stream>>>(w_out, wo_t, DD, DD);

  // qkv GEMM: q -> q_b (phi), k -> kt (phi, transposed), v -> vt (transposed)
  gemm_bt<<<dim3(MM / 256, NQKV / 128), dim3(512), 0, stream>>>(
      x_b, wq_t, b_qkv, (void*)q_b, kt, vt);

  kv_mfma<<<dim3(32, CH), dim3(256), 0, stream>>>(kt, vt, pkv, pks);
  kv_reduce<<<dim3(512), dim3(256), 0, stream>>>(pkv, pks, kv_b, ksum_b);

  // fused attn + output GEMM -> d_out
  attn_out<<<dim3(MM / 64), dim3(256), 0, stream>>>(
      q_b, kv_b, ksum_b, wo_t, b_out, (float*)d_out);
}

// Round 14
// 164.141 us; speedup vs baseline: 1.2457x; 1.2457x over previous
//
#include <hip/hip_runtime.h>
#include <hip/hip_bf16.h>
#include <math.h>

#define BB 4
#define LL 8192
#define DD 512
#define HH 8
#define MM (BB*LL)      // 32768
#define NQKV 1536
#define CH 16           // K-chunks for kv partial reduction (Kc = 512)

typedef __attribute__((ext_vector_type(4))) float f32x4;
typedef __attribute__((ext_vector_type(8))) short s16x8;
typedef __attribute__((ext_vector_type(4))) short s16x4;

__device__ __forceinline__ float bf2f(short u) {
  union { unsigned int i; float f; } c;
  c.i = ((unsigned int)(unsigned short)u) << 16;
  return c.f;
}
__device__ __forceinline__ short f2bf(float f) {
  union { float f; unsigned int i; } c; c.f = f;
  unsigned int r = c.i + 0x7FFFu + ((c.i >> 16) & 1u);
  return (short)(r >> 16);
}

__device__ __forceinline__ void gload16(const void* g, void* l) {
  __builtin_amdgcn_global_load_lds(
      (const __attribute__((address_space(1))) void*)(g),
      (__attribute__((address_space(3))) void*)(l), 16, 0, 0);
}

// ---------------- conversion kernels ----------------
__global__ void conv_bf16(const float* __restrict__ in, short* __restrict__ out, int n) {
  int i = (blockIdx.x * blockDim.x + threadIdx.x) * 8;
  if (i < n) {
    float4 v0 = *reinterpret_cast<const float4*>(in + i);
    float4 v1 = *reinterpret_cast<const float4*>(in + i + 4);
    s16x8 o;
    o[0] = f2bf(v0.x); o[1] = f2bf(v0.y); o[2] = f2bf(v0.z); o[3] = f2bf(v0.w);
    o[4] = f2bf(v1.x); o[5] = f2bf(v1.y); o[6] = f2bf(v1.z); o[7] = f2bf(v1.w);
    *reinterpret_cast<s16x8*>(out + i) = o;
  }
}

// w[K][N] (row-major) -> wt[N][K] bf16
__global__ void conv_wt(const float* __restrict__ w, short* __restrict__ wt, int K, int N) {
  int idx = blockIdx.x * blockDim.x + threadIdx.x;
  if (idx < K * N) {
    int n = idx / K, k = idx - n * K;
    wt[idx] = f2bf(w[(size_t)k * N + n]);
  }
}

// ---------------- bf16 MFMA GEMM (r6-proven), qkv = x @ wqkv^T + bias ----------------
// 256x128 tile, BK=64, 8 waves (4M x 2N), per-wave 64x64 out.  48KB staged LDS,
// 64KB epilogue scratch, m-major XCD chunking (A slice = one XCD's 4MB L2).
// Staging swizzle: row r, 16B-unit u stored at (u ^ (r&7)), pre-swizzled source.
// q cols -> phi + row-major q_b[M][512];
// k cols -> phi + per-head transpose kt[head][dh][8192];
// v cols -> per-head transpose vt[head][m][8192].
__global__ __launch_bounds__(512, 4)
void gemm_bt(const short* __restrict__ A, const short* __restrict__ BT,
             const float* __restrict__ bias, void* __restrict__ Cout,
             short* __restrict__ ktb, short* __restrict__ vtb)
{
  constexpr int KD = 512;
  __shared__ __align__(16) char lds[65536];   // As 32KB | Bs 16KB; epilogue reuses 64KB

  const int tid = threadIdx.x;
  const int wv = tid >> 6, lane = tid & 63;
  const int wm = wv >> 1, wn = wv & 1;        // 4 m-waves x 2 n-waves
  const int fr = lane & 15, fq = lane >> 4;

  // m-major XCD chunking: each XCD owns a contiguous m-stripe
  const int gx = gridDim.x;                   // # m-blocks
  const int gy = gridDim.y;                   // # n-blocks
  const int d = blockIdx.y * gx + blockIdx.x;
  const int nwg = gx * gy;
  const int lin = (d & 7) * (nwg >> 3) + (d >> 3);
  const int m0 = (lin / gy) * 256, n0 = (lin % gy) * 128;

  // staging: rows (tid>>3)+i*64; LDS unit tid&7 holds global unit (tid&7)^(row&7)
  const int srow = tid >> 3;
  const int sunit = (tid & 7) ^ (srow & 7);
  const short* Ag = A  + (size_t)(m0 + srow) * KD + sunit * 8;
  const short* Bg = BT + (size_t)(n0 + srow) * KD + sunit * 8;
  char* ldsw = lds + wv * 1024;               // + lane*16 implicit in gload_lds

  f32x4 acc[4][4] = {};

  for (int t = 0; t < 8; ++t) {
    const int k0 = t * 64;
#pragma unroll
    for (int i = 0; i < 4; ++i)
      gload16(Ag + (size_t)(i * 64) * KD + k0, ldsw + i * 8192);
#pragma unroll
    for (int i = 0; i < 2; ++i)
      gload16(Bg + (size_t)(i * 64) * KD + k0, ldsw + 32768 + i * 8192);
    __syncthreads();
#pragma unroll
    for (int kk = 0; kk < 2; ++kk) {
      s16x8 af[4], bfg[4];
#pragma unroll
      for (int i = 0; i < 4; ++i) {
        const int ra = wm * 64 + i * 16 + fr;
        const int ua = (kk * 4 + fq) ^ (ra & 7);
        af[i] = *(const s16x8*)(lds + ra * 128 + ua * 16);
      }
#pragma unroll
      for (int j = 0; j < 4; ++j) {
        const int rb = wn * 64 + j * 16 + fr;
        const int ub = (kk * 4 + fq) ^ (rb & 7);
        bfg[j] = *(const s16x8*)(lds + 32768 + rb * 128 + ub * 16);
      }
#pragma unroll
      for (int i = 0; i < 4; ++i)
#pragma unroll
        for (int j = 0; j < 4; ++j)
          acc[i][j] = __builtin_amdgcn_mfma_f32_16x16x32_bf16(af[i], bfg[j], acc[i][j], 0, 0, 0);
    }
    __syncthreads();
  }

  // ---- epilogue ----
  if (n0 < 512) {
    // q: phi + row-major bf16 to Cout (q_b), stride 512
    short* scr = (short*)lds;   // 256x128
#pragma unroll
    for (int j = 0; j < 4; ++j) {
      const int col = wn * 64 + j * 16 + fr;
      const float bv = bias[n0 + col];
#pragma unroll
      for (int i = 0; i < 4; ++i) {
        const int row = wm * 64 + i * 16 + fq * 4;
#pragma unroll
        for (int r = 0; r < 4; ++r) {
          float v = acc[i][j][r] + bv;
          v = (v > 0.f) ? (v + 1.f) : __expf(v);   // phi = elu+1
          scr[(row + r) * 128 + col] = f2bf(v);
        }
      }
    }
    __syncthreads();
#pragma unroll
    for (int p = 0; p < 8; ++p) {
      const int off = p * 8192 + tid * 16;          // bytes
      const int row = off >> 8, colb = off & 255;   // 256B per row
      s16x8 v = *(const s16x8*)(lds + off);
      *(s16x8*)((short*)Cout + (size_t)(m0 + row) * 512 + n0 + (colb >> 1)) = v;
    }
  } else {
    // k/v: (phi for k) + per-head transposed write via scr_t[col][l]
    const bool do_phi = (n0 < 1024);
    short* tdst = do_phi ? ktb : vtb;
    const int f0 = n0 - (do_phi ? 512 : 1024);
#pragma unroll
    for (int j = 0; j < 4; ++j) {
      const int col = wn * 64 + j * 16 + fr;
      const float bv = bias[n0 + col];
      const int cx = col & 31;
#pragma unroll
      for (int i = 0; i < 4; ++i) {
        const int l = wm * 64 + i * 16 + fq * 4;
        s16x4 pk;
#pragma unroll
        for (int r = 0; r < 4; ++r) {
          float v = acc[i][j][r] + bv;
          if (do_phi) v = (v > 0.f) ? (v + 1.f) : __expf(v);
          pk[r] = f2bf(v);
        }
        *(s16x4*)(lds + col * 512 + (((l >> 3) ^ cx) * 16) + (l & 7) * 2) = pk;
      }
    }
    __syncthreads();
#pragma unroll
    for (int p = 0; p < 8; ++p) {
      const int g = p * 512 + tid;
      const int col = g >> 5, up = g & 31;
      const int u = up ^ (col & 31);
      s16x8 v = *(const s16x8*)(lds + col * 512 + up * 16);
      const int f = f0 + col;
      const int hb = ((m0 >> 13) << 3) + (f >> 6);
      short* dst = tdst + ((size_t)hb * 64 + (f & 63)) * 8192 + (m0 & 8191) + u * 8;
      *(s16x8*)dst = v;
    }
  }
}

// ---------------- kv partials via MFMA ----------------
__global__ __launch_bounds__(256, 4)
void kv_mfma(const short* __restrict__ kt, const short* __restrict__ vt,
             float* __restrict__ pkv, float* __restrict__ pks)
{
  const int hb = blockIdx.x, c = blockIdx.y;
  const int tid = threadIdx.x, wv = tid >> 6, lane = tid & 63;
  const int fr = lane & 15, fq = lane >> 4;
  const size_t base = (size_t)hb * 64 * 8192;
  const int l0 = c * 512;
  const short* vrow = vt + base + (size_t)fr * 8192 + l0 + fq * 8;
  const short* krow = kt + base + (size_t)(wv * 16 + fr) * 8192 + l0 + fq * 8;

  s16x8 ones;
#pragma unroll
  for (int j = 0; j < 8; ++j) ones[j] = (short)0x3F80;   // bf16 1.0

  f32x4 acc[4] = {};
  f32x4 accd = {};
#pragma unroll
  for (int ks = 0; ks < 16; ++ks) {
    s16x8 bfr = *(const s16x8*)(krow + ks * 32);
    accd = __builtin_amdgcn_mfma_f32_16x16x32_bf16(ones, bfr, accd, 0, 0, 0);
#pragma unroll
    for (int i = 0; i < 4; ++i) {
      s16x8 af = *(const s16x8*)(vrow + (size_t)(i * 16) * 8192 + ks * 32);
      acc[i] = __builtin_amdgcn_mfma_f32_16x16x32_bf16(af, bfr, acc[i], 0, 0, 0);
    }
  }
  float* o = pkv + ((size_t)hb * CH + c) * 4096;
#pragma unroll
  for (int i = 0; i < 4; ++i)
#pragma unroll
    for (int r = 0; r < 4; ++r)
      o[(i * 16 + fq * 4 + r) * 64 + wv * 16 + fr] = acc[i][r];
  if (fq == 0)
    pks[((size_t)hb * CH + c) * 64 + wv * 16 + fr] = accd[0];
}

// reduce partials -> bf16 kv_b [head][m][d], bf16 ksum_b [head][d] (with +1e-6)
__global__ void kv_reduce(const float* __restrict__ pkv, const float* __restrict__ pks,
                          short* __restrict__ kv_b, short* __restrict__ ksum_b)
{
  const int idx = blockIdx.x * 256 + threadIdx.x;   // head*4096 + m*64 + d
  const int head = idx >> 12, md = idx & 4095;
  float s = 0.f;
  for (int i = 0; i < CH; ++i) s += pkv[((size_t)head * CH + i) * 4096 + md];
  kv_b[idx] = f2bf(s);
  if (md < 64) {
    float t = 0.f;
    for (int i = 0; i < CH; ++i) t += pks[((size_t)head * CH + i) * 64 + md];
    ksum_b[head * 64 + md] = f2bf(t + 1e-6f);
  }
}

// ---------------- fused attn + output GEMM (r12-proven) ----------------
__global__ __launch_bounds__(256, 2)
void attn_out(const short* __restrict__ q_b, const short* __restrict__ kv_b,
              const short* __restrict__ ksum_b, const short* __restrict__ wo_t,
              const float* __restrict__ b_out, float* __restrict__ out)
{
  __shared__ __align__(16) char lds[73728];   // At 8KB @0 | Ws 64KB @8192
  const int tid = threadIdx.x;
  const int wv = tid >> 6, lane = tid & 63;
  const int fr = lane & 15, fq = lane >> 4;
  const int l0 = blockIdx.x * 64;
  const int bb = l0 >> 13;                    // batch index

  const int srow = tid >> 3;
  const int sunit = (tid & 7) ^ (srow & 7);
  const short* Wg = wo_t + (size_t)srow * 512 + sunit * 8;
  char* ldsw = lds + 8192 + wv * 1024;        // + lane*16 implicit in gload_lds

  f32x4 acc[4][8] = {};

  for (int h = 0; h < 8; ++h) {
#pragma unroll
    for (int i = 0; i < 16; ++i)
      gload16(Wg + (size_t)(i * 32) * 512 + h * 64, ldsw + i * 4096);

    // ---- phase A: attn for head h, this wave's 16-row slab ----
    {
      const int hb = bb * 8 + h;
      const short* kvp = kv_b + (size_t)hb * 4096;
      const short* ksp = ksum_b + hb * 64;
      const short* qb = q_b + (size_t)(l0 + wv * 16) * 512 + h * 64;
      f32x4 accn[4] = {};
      f32x4 accd = {};
#pragma unroll
      for (int kk = 0; kk < 2; ++kk) {
        s16x8 a = *(const s16x8*)(qb + (size_t)fr * 512 + kk * 32 + fq * 8);
        s16x8 bden = *(const s16x8*)(ksp + kk * 32 + fq * 8);
        accd = __builtin_amdgcn_mfma_f32_16x16x32_bf16(a, bden, accd, 0, 0, 0);
#pragma unroll
        for (int j = 0; j < 4; ++j) {
          s16x8 bfr = *(const s16x8*)(kvp + (j * 16 + fr) * 64 + kk * 32 + fq * 8);
          accn[j] = __builtin_amdgcn_mfma_f32_16x16x32_bf16(a, bfr, accn[j], 0, 0, 0);
        }
      }
#pragma unroll
      for (int r = 0; r < 4; ++r) {
        const int row = wv * 16 + fq * 4 + r;
        const float dinv = 1.0f / accd[r];
#pragma unroll
        for (int j = 0; j < 4; ++j) {
          const int col = j * 16 + fr;
          *(short*)(lds + row * 128 + (((col >> 3) ^ (row & 7)) << 4) + ((col & 7) << 1))
              = f2bf(accn[j][r] * dinv);
        }
      }
    }
    __syncthreads();   // At ready + Ws landed

    // ---- phase B: acc += At @ Ws^T over this chunk's K=64 ----
#pragma unroll
    for (int kk = 0; kk < 2; ++kk) {
      s16x8 af[4];
#pragma unroll
      for (int i = 0; i < 4; ++i) {
        const int row = i * 16 + fr;
        const int u = (kk * 4 + fq) ^ (row & 7);
        af[i] = *(const s16x8*)(lds + row * 128 + u * 16);
      }
#pragma unroll
      for (int j = 0; j < 8; ++j) {
        const int n = wv * 128 + j * 16 + fr;
        const int u = (kk * 4 + fq) ^ (n & 7);
        s16x8 bw = *(const s16x8*)(lds + 8192 + n * 128 + u * 16);
#pragma unroll
        for (int i = 0; i < 4; ++i)
          acc[i][j] = __builtin_amdgcn_mfma_f32_16x16x32_bf16(af[i], bw, acc[i][j], 0, 0, 0);
      }
    }
    __syncthreads();   // protect At/Ws for next chunk
  }

  // ---- epilogue: 2 passes of 32 rows through 64KB fp32 scratch ----
  float* scrf = (float*)lds;
#pragma unroll
  for (int p = 0; p < 2; ++p) {
#pragma unroll
    for (int ii = 0; ii < 2; ++ii) {
      const int i = 2 * p + ii;
#pragma unroll
      for (int j = 0; j < 8; ++j) {
        const int col = wv * 128 + j * 16 + fr;
        const float bv = b_out[col];
#pragma unroll
        for (int r = 0; r < 4; ++r)
          scrf[(ii * 16 + fq * 4 + r) * 512 + col] = acc[i][j][r] + bv;
      }
    }
    __syncthreads();
#pragma unroll
    for (int pp = 0; pp < 16; ++pp) {
      const int off = pp * 4096 + tid * 16;
      const int row = off >> 11, colb = off & 2047;   // 2KB per row (512 fp32)
      float4 v = *(const float4*)(lds + off);
      *(float4*)(out + (size_t)(l0 + p * 32 + row) * 512 + (colb >> 2)) = v;
    }
    __syncthreads();
  }
}

// ---------------- launch ----------------
extern "C" void kernel_launch(void* const* d_in, const int* in_sizes, int n_in,
                              void* d_out, int out_size, void* d_ws, size_t ws_size,
                              hipStream_t stream)
{
  const float* x     = (const float*)d_in[0];
  const float* w_qkv = (const float*)d_in[1];
  const float* b_qkv = (const float*)d_in[2];
  const float* w_out = (const float*)d_in[3];
  const float* b_out = (const float*)d_in[4];

  char* ws = (char*)d_ws;
  size_t off = 0;
  short* x_b   = (short*)(ws + off); off += (size_t)MM * DD * 2;        // 32 MB
  short* wq_t  = (short*)(ws + off); off += (size_t)NQKV * DD * 2;      // 1.5 MB
  short* wo_t  = (short*)(ws + off); off += (size_t)DD * DD * 2;        // 0.5 MB
  short* q_b   = (short*)(ws + off); off += (size_t)MM * DD * 2;        // 32 MB
  short* kt    = (short*)(ws + off); off += (size_t)32 * 64 * LL * 2;   // 32 MB
  short* vt    = (short*)(ws + off); off += (size_t)32 * 64 * LL * 2;   // 32 MB
  float* pkv   = (float*)(ws + off); off += (size_t)32 * CH * 4096 * 4; // 8 MB
  float* pks   = (float*)(ws + off); off += (size_t)32 * CH * 64 * 4;   // 0.13 MB
  short* kv_b  = (short*)(ws + off); off += (size_t)32 * 4096 * 2;      // 0.25 MB
  short* ksum_b= (short*)(ws + off); off += (size_t)32 * 64 * 2;        // 4 KB

  conv_bf16<<<dim3(MM * DD / 8 / 256), dim3(256), 0, stream>>>(x, x_b, MM * DD);
  conv_wt<<<dim3((DD * NQKV + 255) / 256), dim3(256), 0, stream>>>(w_qkv, wq_t, DD, NQKV);
  conv_wt<<<dim3((DD * DD + 255) / 256), dim3(256), 0, stream>>>(w_out, wo_t, DD, DD);

  // qkv GEMM: q -> q_b (phi), k -> kt (phi, transposed), v -> vt (transposed)
  gemm_bt<<<dim3(MM / 256, NQKV / 128), dim3(512), 0, stream>>>(
      x_b, wq_t, b_qkv, (void*)q_b, kt, vt);

  kv_mfma<<<dim3(32, CH), dim3(256), 0, stream>>>(kt, vt, pkv, pks);
  kv_reduce<<<dim3(512), dim3(256), 0, stream>>>(pkv, pks, kv_b, ksum_b);

  // fused attn + output GEMM -> d_out
  attn_out<<<dim3(MM / 64), dim3(256), 0, stream>>>(
      q_b, kv_b, ksum_b, wo_t, b_out, (float*)d_out);
}

// Round 15
// 162.882 us; speedup vs baseline: 1.2553x; 1.0077x over previous
//
#include <hip/hip_runtime.h>
#include <hip/hip_bf16.h>
#include <math.h>

#define BB 4
#define LL 8192
#define DD 512
#define HH 8
#define MM (BB*LL)      // 32768
#define NQKV 1536
#define CH 16           // K-chunks for kv partial reduction (Kc = 512)

typedef __attribute__((ext_vector_type(4))) float f32x4;
typedef __attribute__((ext_vector_type(8))) short s16x8;
typedef __attribute__((ext_vector_type(4))) short s16x4;

__device__ __forceinline__ float bf2f(short u) {
  union { unsigned int i; float f; } c;
  c.i = ((unsigned int)(unsigned short)u) << 16;
  return c.f;
}
__device__ __forceinline__ short f2bf(float f) {
  union { float f; unsigned int i; } c; c.f = f;
  unsigned int r = c.i + 0x7FFFu + ((c.i >> 16) & 1u);
  return (short)(r >> 16);
}

__device__ __forceinline__ void gload16(const void* g, void* l) {
  __builtin_amdgcn_global_load_lds(
      (const __attribute__((address_space(1))) void*)(g),
      (__attribute__((address_space(3))) void*)(l), 16, 0, 0);
}

// ---------------- fused conversion kernel (one dispatch) ----------------
// blocks [0, 8192): x fp32 -> bf16, 8 elems/thread
// blocks [8192, 11264): w_qkv [512][1536] -> wq_t [1536][512] bf16
// blocks [11264, 12288): w_out [512][512] -> wo_t [512][512] bf16
__global__ void conv_all(const float* __restrict__ x, const float* __restrict__ wq,
                         const float* __restrict__ wo, short* __restrict__ x_b,
                         short* __restrict__ wq_t, short* __restrict__ wo_t)
{
  const int b = blockIdx.x, tid = threadIdx.x;
  if (b < 8192) {
    const int i = (b * 256 + tid) * 8;
    float4 v0 = *reinterpret_cast<const float4*>(x + i);
    float4 v1 = *reinterpret_cast<const float4*>(x + i + 4);
    s16x8 o;
    o[0] = f2bf(v0.x); o[1] = f2bf(v0.y); o[2] = f2bf(v0.z); o[3] = f2bf(v0.w);
    o[4] = f2bf(v1.x); o[5] = f2bf(v1.y); o[6] = f2bf(v1.z); o[7] = f2bf(v1.w);
    *reinterpret_cast<s16x8*>(x_b + i) = o;
  } else if (b < 11264) {
    const int idx = (b - 8192) * 256 + tid;      // n*512 + k
    const int n = idx >> 9, k = idx & 511;
    wq_t[idx] = f2bf(wq[(size_t)k * NQKV + n]);
  } else {
    const int idx = (b - 11264) * 256 + tid;
    const int n = idx >> 9, k = idx & 511;
    wo_t[idx] = f2bf(wo[(size_t)k * DD + n]);
  }
}

// ---------------- bf16 MFMA GEMM (r6-proven), qkv = x @ wqkv^T + bias ----------------
// 256x128 tile, BK=64, 8 waves (4M x 2N), per-wave 64x64 out.  48KB staged LDS,
// 64KB epilogue scratch, m-major XCD chunking (A slice = one XCD's 4MB L2).
// Staging swizzle: row r, 16B-unit u stored at (u ^ (r&7)), pre-swizzled source.
__global__ __launch_bounds__(512, 4)
void gemm_bt(const short* __restrict__ A, const short* __restrict__ BT,
             const float* __restrict__ bias, void* __restrict__ Cout,
             short* __restrict__ ktb, short* __restrict__ vtb)
{
  constexpr int KD = 512;
  __shared__ __align__(16) char lds[65536];   // As 32KB | Bs 16KB; epilogue reuses 64KB

  const int tid = threadIdx.x;
  const int wv = tid >> 6, lane = tid & 63;
  const int wm = wv >> 1, wn = wv & 1;        // 4 m-waves x 2 n-waves
  const int fr = lane & 15, fq = lane >> 4;

  const int gx = gridDim.x, gy = gridDim.y;
  const int d = blockIdx.y * gx + blockIdx.x;
  const int nwg = gx * gy;
  const int lin = (d & 7) * (nwg >> 3) + (d >> 3);
  const int m0 = (lin / gy) * 256, n0 = (lin % gy) * 128;

  const int srow = tid >> 3;
  const int sunit = (tid & 7) ^ (srow & 7);
  const short* Ag = A  + (size_t)(m0 + srow) * KD + sunit * 8;
  const short* Bg = BT + (size_t)(n0 + srow) * KD + sunit * 8;
  char* ldsw = lds + wv * 1024;               // + lane*16 implicit in gload_lds

  f32x4 acc[4][4] = {};

  for (int t = 0; t < 8; ++t) {
    const int k0 = t * 64;
#pragma unroll
    for (int i = 0; i < 4; ++i)
      gload16(Ag + (size_t)(i * 64) * KD + k0, ldsw + i * 8192);
#pragma unroll
    for (int i = 0; i < 2; ++i)
      gload16(Bg + (size_t)(i * 64) * KD + k0, ldsw + 32768 + i * 8192);
    __syncthreads();
#pragma unroll
    for (int kk = 0; kk < 2; ++kk) {
      s16x8 af[4], bfg[4];
#pragma unroll
      for (int i = 0; i < 4; ++i) {
        const int ra = wm * 64 + i * 16 + fr;
        const int ua = (kk * 4 + fq) ^ (ra & 7);
        af[i] = *(const s16x8*)(lds + ra * 128 + ua * 16);
      }
#pragma unroll
      for (int j = 0; j < 4; ++j) {
        const int rb = wn * 64 + j * 16 + fr;
        const int ub = (kk * 4 + fq) ^ (rb & 7);
        bfg[j] = *(const s16x8*)(lds + 32768 + rb * 128 + ub * 16);
      }
#pragma unroll
      for (int i = 0; i < 4; ++i)
#pragma unroll
        for (int j = 0; j < 4; ++j)
          acc[i][j] = __builtin_amdgcn_mfma_f32_16x16x32_bf16(af[i], bfg[j], acc[i][j], 0, 0, 0);
    }
    __syncthreads();
  }

  // ---- epilogue ----
  if (n0 < 512) {
    short* scr = (short*)lds;   // 256x128
#pragma unroll
    for (int j = 0; j < 4; ++j) {
      const int col = wn * 64 + j * 16 + fr;
      const float bv = bias[n0 + col];
#pragma unroll
      for (int i = 0; i < 4; ++i) {
        const int row = wm * 64 + i * 16 + fq * 4;
#pragma unroll
        for (int r = 0; r < 4; ++r) {
          float v = acc[i][j][r] + bv;
          v = (v > 0.f) ? (v + 1.f) : __expf(v);   // phi = elu+1
          scr[(row + r) * 128 + col] = f2bf(v);
        }
      }
    }
    __syncthreads();
#pragma unroll
    for (int p = 0; p < 8; ++p) {
      const int off = p * 8192 + tid * 16;          // bytes
      const int row = off >> 8, colb = off & 255;   // 256B per row
      s16x8 v = *(const s16x8*)(lds + off);
      *(s16x8*)((short*)Cout + (size_t)(m0 + row) * 512 + n0 + (colb >> 1)) = v;
    }
  } else {
    const bool do_phi = (n0 < 1024);
    short* tdst = do_phi ? ktb : vtb;
    const int f0 = n0 - (do_phi ? 512 : 1024);
#pragma unroll
    for (int j = 0; j < 4; ++j) {
      const int col = wn * 64 + j * 16 + fr;
      const float bv = bias[n0 + col];
      const int cx = col & 31;
#pragma unroll
      for (int i = 0; i < 4; ++i) {
        const int l = wm * 64 + i * 16 + fq * 4;
        s16x4 pk;
#pragma unroll
        for (int r = 0; r < 4; ++r) {
          float v = acc[i][j][r] + bv;
          if (do_phi) v = (v > 0.f) ? (v + 1.f) : __expf(v);
          pk[r] = f2bf(v);
        }
        *(s16x4*)(lds + col * 512 + (((l >> 3) ^ cx) * 16) + (l & 7) * 2) = pk;
      }
    }
    __syncthreads();
#pragma unroll
    for (int p = 0; p < 8; ++p) {
      const int g = p * 512 + tid;
      const int col = g >> 5, up = g & 31;
      const int u = up ^ (col & 31);
      s16x8 v = *(const s16x8*)(lds + col * 512 + up * 16);
      const int f = f0 + col;
      const int hb = ((m0 >> 13) << 3) + (f >> 6);
      short* dst = tdst + ((size_t)hb * 64 + (f & 63)) * 8192 + (m0 & 8191) + u * 8;
      *(s16x8*)dst = v;
    }
  }
}

// ---------------- kv partials via MFMA ----------------
__global__ __launch_bounds__(256, 4)
void kv_mfma(const short* __restrict__ kt, const short* __restrict__ vt,
             float* __restrict__ pkv, float* __restrict__ pks)
{
  const int hb = blockIdx.x, c = blockIdx.y;
  const int tid = threadIdx.x, wv = tid >> 6, lane = tid & 63;
  const int fr = lane & 15, fq = lane >> 4;
  const size_t base = (size_t)hb * 64 * 8192;
  const int l0 = c * 512;
  const short* vrow = vt + base + (size_t)fr * 8192 + l0 + fq * 8;
  const short* krow = kt + base + (size_t)(wv * 16 + fr) * 8192 + l0 + fq * 8;

  s16x8 ones;
#pragma unroll
  for (int j = 0; j < 8; ++j) ones[j] = (short)0x3F80;   // bf16 1.0

  f32x4 acc[4] = {};
  f32x4 accd = {};
#pragma unroll
  for (int ks = 0; ks < 16; ++ks) {
    s16x8 bfr = *(const s16x8*)(krow + ks * 32);
    accd = __builtin_amdgcn_mfma_f32_16x16x32_bf16(ones, bfr, accd, 0, 0, 0);
#pragma unroll
    for (int i = 0; i < 4; ++i) {
      s16x8 af = *(const s16x8*)(vrow + (size_t)(i * 16) * 8192 + ks * 32);
      acc[i] = __builtin_amdgcn_mfma_f32_16x16x32_bf16(af, bfr, acc[i], 0, 0, 0);
    }
  }
  float* o = pkv + ((size_t)hb * CH + c) * 4096;
#pragma unroll
  for (int i = 0; i < 4; ++i)
#pragma unroll
    for (int r = 0; r < 4; ++r)
      o[(i * 16 + fq * 4 + r) * 64 + wv * 16 + fr] = acc[i][r];
  if (fq == 0)
    pks[((size_t)hb * CH + c) * 64 + wv * 16 + fr] = accd[0];
}

// reduce partials -> bf16 kv_b [head][m][d], bf16 ksum_b [head][d] (with +1e-6)
__global__ void kv_reduce(const float* __restrict__ pkv, const float* __restrict__ pks,
                          short* __restrict__ kv_b, short* __restrict__ ksum_b)
{
  const int idx = blockIdx.x * 256 + threadIdx.x;   // head*4096 + m*64 + d
  const int head = idx >> 12, md = idx & 4095;
  float s = 0.f;
  for (int i = 0; i < CH; ++i) s += pkv[((size_t)head * CH + i) * 4096 + md];
  kv_b[idx] = f2bf(s);
  if (md < 64) {
    float t = 0.f;
    for (int i = 0; i < CH; ++i) t += pks[((size_t)head * CH + i) * 64 + md];
    ksum_b[head * 64 + md] = f2bf(t + 1e-6f);
  }
}

// ---------------- fused attn + output GEMM (128 rows / 512 threads) ----------------
// Per block: 128 rows, 8 waves, LDS 80KB (At 16KB @0 | Ws 64KB @16384).
// Per head h: stage Ws = wo_t[:, h*64..+63] (8x gload_lds rounds); each wave
// computes its 16-row attn slab (r12-proven MFMA pattern) -> At[128][64] swizzled;
// barrier; phase B: wave (wm2=wv>>2, wn2=wv&3) does 64x128 of out += At @ Ws^T.
// Halves Ws L2 re-staging vs the 64-row version (256 blocks instead of 512).
__global__ __launch_bounds__(512, 2)
void attn_out(const short* __restrict__ q_b, const short* __restrict__ kv_b,
              const short* __restrict__ ksum_b, const short* __restrict__ wo_t,
              const float* __restrict__ b_out, float* __restrict__ out)
{
  __shared__ __align__(16) char lds[81920];   // At 16KB @0 | Ws 64KB @16384
  const int tid = threadIdx.x;
  const int wv = tid >> 6, lane = tid & 63;
  const int fr = lane & 15, fq = lane >> 4;
  const int l0 = blockIdx.x * 128;
  const int bb = l0 >> 13;                    // batch index

  const int srow = tid >> 3;                  // 0..63
  const int sunit = (tid & 7) ^ (srow & 7);
  const short* Wg = wo_t + (size_t)srow * 512 + sunit * 8;
  char* ldsw = lds + 16384 + wv * 1024;       // + lane*16 implicit in gload_lds

  f32x4 acc[4][8] = {};

  for (int h = 0; h < 8; ++h) {
    // stage Ws chunk: 8 rounds x 64 rows (512 thr x 16B = 8KB/round)
#pragma unroll
    for (int i = 0; i < 8; ++i)
      gload16(Wg + (size_t)(i * 64) * 512 + h * 64, ldsw + i * 8192);

    // ---- phase A: attn for head h, this wave's 16-row slab ----
    {
      const int hb = bb * 8 + h;
      const short* kvp = kv_b + (size_t)hb * 4096;
      const short* ksp = ksum_b + hb * 64;
      const short* qb = q_b + (size_t)(l0 + wv * 16) * 512 + h * 64;
      f32x4 accn[4] = {};
      f32x4 accd = {};
#pragma unroll
      for (int kk = 0; kk < 2; ++kk) {
        s16x8 a = *(const s16x8*)(qb + (size_t)fr * 512 + kk * 32 + fq * 8);
        s16x8 bden = *(const s16x8*)(ksp + kk * 32 + fq * 8);
        accd = __builtin_amdgcn_mfma_f32_16x16x32_bf16(a, bden, accd, 0, 0, 0);
#pragma unroll
        for (int j = 0; j < 4; ++j) {
          s16x8 bfr = *(const s16x8*)(kvp + (j * 16 + fr) * 64 + kk * 32 + fq * 8);
          accn[j] = __builtin_amdgcn_mfma_f32_16x16x32_bf16(a, bfr, accn[j], 0, 0, 0);
        }
      }
      // write At[128][64] bf16 (row stride 128B, unit swizzle ^(row&7))
#pragma unroll
      for (int r = 0; r < 4; ++r) {
        const int row = wv * 16 + fq * 4 + r;
        const float dinv = 1.0f / accd[r];
#pragma unroll
        for (int j = 0; j < 4; ++j) {
          const int col = j * 16 + fr;
          *(short*)(lds + row * 128 + (((col >> 3) ^ (row & 7)) << 4) + ((col & 7) << 1))
              = f2bf(accn[j][r] * dinv);
        }
      }
    }
    __syncthreads();   // At ready + Ws landed

    // ---- phase B: wave tile 64x128, acc += At @ Ws^T over K=64 ----
    const int wm2 = wv >> 2, wn2 = wv & 3;
#pragma unroll
    for (int kk = 0; kk < 2; ++kk) {
      s16x8 af[4];
#pragma unroll
      for (int i = 0; i < 4; ++i) {
        const int row = wm2 * 64 + i * 16 + fr;
        const int u = (kk * 4 + fq) ^ (row & 7);
        af[i] = *(const s16x8*)(lds + row * 128 + u * 16);
      }
#pragma unroll
      for (int j = 0; j < 8; ++j) {
        const int n = wn2 * 128 + j * 16 + fr;
        const int u = (kk * 4 + fq) ^ (n & 7);
        s16x8 bw = *(const s16x8*)(lds + 16384 + n * 128 + u * 16);
#pragma unroll
        for (int i = 0; i < 4; ++i)
          acc[i][j] = __builtin_amdgcn_mfma_f32_16x16x32_bf16(af[i], bw, acc[i][j], 0, 0, 0);
      }
    }
    __syncthreads();   // protect At/Ws for next chunk
  }

  // ---- epilogue: 4 passes of 32 rows through 64KB fp32 scratch ----
  const int wm2 = wv >> 2, wn2 = wv & 3;
  float* scrf = (float*)lds;
#pragma unroll
  for (int p = 0; p < 4; ++p) {
    if (wm2 == (p >> 1)) {
#pragma unroll
      for (int ii = 0; ii < 2; ++ii) {
        const int i = (p & 1) * 2 + ii;
#pragma unroll
        for (int j = 0; j < 8; ++j) {
          const int col = wn2 * 128 + j * 16 + fr;
          const float bv = b_out[col];
#pragma unroll
          for (int r = 0; r < 4; ++r)
            scrf[(ii * 16 + fq * 4 + r) * 512 + col] = acc[i][j][r] + bv;
        }
      }
    }
    __syncthreads();
#pragma unroll
    for (int pp = 0; pp < 8; ++pp) {
      const int off = pp * 8192 + tid * 16;
      const int row = off >> 11, colb = off & 2047;   // 2KB per row (512 fp32)
      float4 v = *(const float4*)(lds + off);
      *(float4*)(out + (size_t)(l0 + p * 32 + row) * 512 + (colb >> 2)) = v;
    }
    __syncthreads();
  }
}

// ---------------- launch ----------------
extern "C" void kernel_launch(void* const* d_in, const int* in_sizes, int n_in,
                              void* d_out, int out_size, void* d_ws, size_t ws_size,
                              hipStream_t stream)
{
  const float* x     = (const float*)d_in[0];
  const float* w_qkv = (const float*)d_in[1];
  const float* b_qkv = (const float*)d_in[2];
  const float* w_out = (const float*)d_in[3];
  const float* b_out = (const float*)d_in[4];

  char* ws = (char*)d_ws;
  size_t off = 0;
  short* x_b   = (short*)(ws + off); off += (size_t)MM * DD * 2;        // 32 MB
  short* wq_t  = (short*)(ws + off); off += (size_t)NQKV * DD * 2;      // 1.5 MB
  short* wo_t  = (short*)(ws + off); off += (size_t)DD * DD * 2;        // 0.5 MB
  short* q_b   = (short*)(ws + off); off += (size_t)MM * DD * 2;        // 32 MB
  short* kt    = (short*)(ws + off); off += (size_t)32 * 64 * LL * 2;   // 32 MB
  short* vt    = (short*)(ws + off); off += (size_t)32 * 64 * LL * 2;   // 32 MB
  float* pkv   = (float*)(ws + off); off += (size_t)32 * CH * 4096 * 4; // 8 MB
  float* pks   = (float*)(ws + off); off += (size_t)32 * CH * 64 * 4;   // 0.13 MB
  short* kv_b  = (short*)(ws + off); off += (size_t)32 * 4096 * 2;      // 0.25 MB
  short* ksum_b= (short*)(ws + off); off += (size_t)32 * 64 * 2;        // 4 KB

  // fused conversions: x -> bf16, weights -> transposed bf16
  conv_all<<<dim3(12288), dim3(256), 0, stream>>>(x, w_qkv, w_out, x_b, wq_t, wo_t);

  // qkv GEMM: q -> q_b (phi), k -> kt (phi, transposed), v -> vt (transposed)
  gemm_bt<<<dim3(MM / 256, NQKV / 128), dim3(512), 0, stream>>>(
      x_b, wq_t, b_qkv, (void*)q_b, kt, vt);

  kv_mfma<<<dim3(32, CH), dim3(256), 0, stream>>>(kt, vt, pkv, pks);
  kv_reduce<<<dim3(512), dim3(256), 0, stream>>>(pkv, pks, kv_b, ksum_b);

  // fused attn + output GEMM -> d_out
  attn_out<<<dim3(MM / 128), dim3(512), 0, stream>>>(
      q_b, kv_b, ksum_b, wo_t, b_out, (float*)d_out);
}

// Round 16
// 161.962 us; speedup vs baseline: 1.2624x; 1.0057x over previous
//
#include <hip/hip_runtime.h>
#include <hip/hip_bf16.h>
#include <math.h>

#define BB 4
#define LL 8192
#define DD 512
#define HH 8
#define MM (BB*LL)      // 32768
#define NQKV 1536
#define CH 16           // K-chunks for kv partial reduction (Kc = 512)

typedef __attribute__((ext_vector_type(4))) float f32x4;
typedef __attribute__((ext_vector_type(8))) short s16x8;
typedef __attribute__((ext_vector_type(4))) short s16x4;

__device__ __forceinline__ float bf2f(short u) {
  union { unsigned int i; float f; } c;
  c.i = ((unsigned int)(unsigned short)u) << 16;
  return c.f;
}
__device__ __forceinline__ short f2bf(float f) {
  union { float f; unsigned int i; } c; c.f = f;
  unsigned int r = c.i + 0x7FFFu + ((c.i >> 16) & 1u);
  return (short)(r >> 16);
}

__device__ __forceinline__ void gload16(const void* g, void* l) {
  __builtin_amdgcn_global_load_lds(
      (const __attribute__((address_space(1))) void*)(g),
      (__attribute__((address_space(3))) void*)(l), 16, 0, 0);
}

// ---------------- fused conversion kernel (one dispatch) ----------------
// blocks [0, 8192): x fp32 -> bf16, 8 elems/thread (BW-bound, coalesced)
// blocks [8192, 8960): w_qkv [512][1536] -> wq_t [1536][512], 32x32 LDS transpose
// blocks [8960, 9216): w_out [512][512] -> wo_t [512][512], 32x32 LDS transpose
// Transpose is coalesced on BOTH sides (r15's version read 4B at 6KB stride).
__global__ void conv_all(const float* __restrict__ x, const float* __restrict__ wq,
                         const float* __restrict__ wo, short* __restrict__ x_b,
                         short* __restrict__ wq_t, short* __restrict__ wo_t)
{
  __shared__ float tile[32][33];   // +1 pad: conflict-free transposed reads
  const int b = blockIdx.x, tid = threadIdx.x;
  if (b < 8192) {
    const int i = (b * 256 + tid) * 8;
    float4 v0 = *reinterpret_cast<const float4*>(x + i);
    float4 v1 = *reinterpret_cast<const float4*>(x + i + 4);
    s16x8 o;
    o[0] = f2bf(v0.x); o[1] = f2bf(v0.y); o[2] = f2bf(v0.z); o[3] = f2bf(v0.w);
    o[4] = f2bf(v1.x); o[5] = f2bf(v1.y); o[6] = f2bf(v1.z); o[7] = f2bf(v1.w);
    *reinterpret_cast<s16x8*>(x_b + i) = o;
  } else {
    int tb = b - 8192;
    const float* src;
    short* dst;
    int N;
    if (tb < 768) { src = wq; dst = wq_t; N = NQKV; }          // 16 x 48 tiles
    else          { tb -= 768; src = wo; dst = wo_t; N = DD; } // 16 x 16 tiles
    const int ntn = N >> 5;
    const int k0 = (tb / ntn) * 32, n0 = (tb % ntn) * 32;
    const int r = tid >> 5, c = tid & 31;   // 8 rows x 32 cols per pass
#pragma unroll
    for (int p = 0; p < 4; ++p)
      tile[p * 8 + r][c] = src[(size_t)(k0 + p * 8 + r) * N + n0 + c];
    __syncthreads();
    // dst[n][k] = w[k][n]: row n0+p*8+r, col k0+c  (consecutive c -> consecutive k)
#pragma unroll
    for (int p = 0; p < 4; ++p)
      dst[(size_t)(n0 + p * 8 + r) * 512 + k0 + c] = f2bf(tile[c][p * 8 + r]);
  }
}

// ---------------- bf16 MFMA GEMM (r6-proven), qkv = x @ wqkv^T + bias ----------------
// 256x128 tile, BK=64, 8 waves (4M x 2N), per-wave 64x64 out.  48KB staged LDS,
// 64KB epilogue scratch, m-major XCD chunking (A slice = one XCD's 4MB L2).
// Staging swizzle: row r, 16B-unit u stored at (u ^ (r&7)), pre-swizzled source.
__global__ __launch_bounds__(512, 4)
void gemm_bt(const short* __restrict__ A, const short* __restrict__ BT,
             const float* __restrict__ bias, void* __restrict__ Cout,
             short* __restrict__ ktb, short* __restrict__ vtb)
{
  constexpr int KD = 512;
  __shared__ __align__(16) char lds[65536];   // As 32KB | Bs 16KB; epilogue reuses 64KB

  const int tid = threadIdx.x;
  const int wv = tid >> 6, lane = tid & 63;
  const int wm = wv >> 1, wn = wv & 1;        // 4 m-waves x 2 n-waves
  const int fr = lane & 15, fq = lane >> 4;

  const int gx = gridDim.x, gy = gridDim.y;
  const int d = blockIdx.y * gx + blockIdx.x;
  const int nwg = gx * gy;
  const int lin = (d & 7) * (nwg >> 3) + (d >> 3);
  const int m0 = (lin / gy) * 256, n0 = (lin % gy) * 128;

  const int srow = tid >> 3;
  const int sunit = (tid & 7) ^ (srow & 7);
  const short* Ag = A  + (size_t)(m0 + srow) * KD + sunit * 8;
  const short* Bg = BT + (size_t)(n0 + srow) * KD + sunit * 8;
  char* ldsw = lds + wv * 1024;               // + lane*16 implicit in gload_lds

  f32x4 acc[4][4] = {};

  for (int t = 0; t < 8; ++t) {
    const int k0 = t * 64;
#pragma unroll
    for (int i = 0; i < 4; ++i)
      gload16(Ag + (size_t)(i * 64) * KD + k0, ldsw + i * 8192);
#pragma unroll
    for (int i = 0; i < 2; ++i)
      gload16(Bg + (size_t)(i * 64) * KD + k0, ldsw + 32768 + i * 8192);
    __syncthreads();
#pragma unroll
    for (int kk = 0; kk < 2; ++kk) {
      s16x8 af[4], bfg[4];
#pragma unroll
      for (int i = 0; i < 4; ++i) {
        const int ra = wm * 64 + i * 16 + fr;
        const int ua = (kk * 4 + fq) ^ (ra & 7);
        af[i] = *(const s16x8*)(lds + ra * 128 + ua * 16);
      }
#pragma unroll
      for (int j = 0; j < 4; ++j) {
        const int rb = wn * 64 + j * 16 + fr;
        const int ub = (kk * 4 + fq) ^ (rb & 7);
        bfg[j] = *(const s16x8*)(lds + 32768 + rb * 128 + ub * 16);
      }
#pragma unroll
      for (int i = 0; i < 4; ++i)
#pragma unroll
        for (int j = 0; j < 4; ++j)
          acc[i][j] = __builtin_amdgcn_mfma_f32_16x16x32_bf16(af[i], bfg[j], acc[i][j], 0, 0, 0);
    }
    __syncthreads();
  }

  // ---- epilogue ----
  if (n0 < 512) {
    short* scr = (short*)lds;   // 256x128
#pragma unroll
    for (int j = 0; j < 4; ++j) {
      const int col = wn * 64 + j * 16 + fr;
      const float bv = bias[n0 + col];
#pragma unroll
      for (int i = 0; i < 4; ++i) {
        const int row = wm * 64 + i * 16 + fq * 4;
#pragma unroll
        for (int r = 0; r < 4; ++r) {
          float v = acc[i][j][r] + bv;
          v = (v > 0.f) ? (v + 1.f) : __expf(v);   // phi = elu+1
          scr[(row + r) * 128 + col] = f2bf(v);
        }
      }
    }
    __syncthreads();
#pragma unroll
    for (int p = 0; p < 8; ++p) {
      const int off = p * 8192 + tid * 16;          // bytes
      const int row = off >> 8, colb = off & 255;   // 256B per row
      s16x8 v = *(const s16x8*)(lds + off);
      *(s16x8*)((short*)Cout + (size_t)(m0 + row) * 512 + n0 + (colb >> 1)) = v;
    }
  } else {
    const bool do_phi = (n0 < 1024);
    short* tdst = do_phi ? ktb : vtb;
    const int f0 = n0 - (do_phi ? 512 : 1024);
#pragma unroll
    for (int j = 0; j < 4; ++j) {
      const int col = wn * 64 + j * 16 + fr;
      const float bv = bias[n0 + col];
      const int cx = col & 31;
#pragma unroll
      for (int i = 0; i < 4; ++i) {
        const int l = wm * 64 + i * 16 + fq * 4;
        s16x4 pk;
#pragma unroll
        for (int r = 0; r < 4; ++r) {
          float v = acc[i][j][r] + bv;
          if (do_phi) v = (v > 0.f) ? (v + 1.f) : __expf(v);
          pk[r] = f2bf(v);
        }
        *(s16x4*)(lds + col * 512 + (((l >> 3) ^ cx) * 16) + (l & 7) * 2) = pk;
      }
    }
    __syncthreads();
#pragma unroll
    for (int p = 0; p < 8; ++p) {
      const int g = p * 512 + tid;
      const int col = g >> 5, up = g & 31;
      const int u = up ^ (col & 31);
      s16x8 v = *(const s16x8*)(lds + col * 512 + up * 16);
      const int f = f0 + col;
      const int hb = ((m0 >> 13) << 3) + (f >> 6);
      short* dst = tdst + ((size_t)hb * 64 + (f & 63)) * 8192 + (m0 & 8191) + u * 8;
      *(s16x8*)dst = v;
    }
  }
}

// ---------------- kv partials via MFMA ----------------
__global__ __launch_bounds__(256, 4)
void kv_mfma(const short* __restrict__ kt, const short* __restrict__ vt,
             float* __restrict__ pkv, float* __restrict__ pks)
{
  const int hb = blockIdx.x, c = blockIdx.y;
  const int tid = threadIdx.x, wv = tid >> 6, lane = tid & 63;
  const int fr = lane & 15, fq = lane >> 4;
  const size_t base = (size_t)hb * 64 * 8192;
  const int l0 = c * 512;
  const short* vrow = vt + base + (size_t)fr * 8192 + l0 + fq * 8;
  const short* krow = kt + base + (size_t)(wv * 16 + fr) * 8192 + l0 + fq * 8;

  s16x8 ones;
#pragma unroll
  for (int j = 0; j < 8; ++j) ones[j] = (short)0x3F80;   // bf16 1.0

  f32x4 acc[4] = {};
  f32x4 accd = {};
#pragma unroll
  for (int ks = 0; ks < 16; ++ks) {
    s16x8 bfr = *(const s16x8*)(krow + ks * 32);
    accd = __builtin_amdgcn_mfma_f32_16x16x32_bf16(ones, bfr, accd, 0, 0, 0);
#pragma unroll
    for (int i = 0; i < 4; ++i) {
      s16x8 af = *(const s16x8*)(vrow + (size_t)(i * 16) * 8192 + ks * 32);
      acc[i] = __builtin_amdgcn_mfma_f32_16x16x32_bf16(af, bfr, acc[i], 0, 0, 0);
    }
  }
  float* o = pkv + ((size_t)hb * CH + c) * 4096;
#pragma unroll
  for (int i = 0; i < 4; ++i)
#pragma unroll
    for (int r = 0; r < 4; ++r)
      o[(i * 16 + fq * 4 + r) * 64 + wv * 16 + fr] = acc[i][r];
  if (fq == 0)
    pks[((size_t)hb * CH + c) * 64 + wv * 16 + fr] = accd[0];
}

// reduce partials -> bf16 kv_b [head][m][d], bf16 ksum_b [head][d] (with +1e-6)
__global__ void kv_reduce(const float* __restrict__ pkv, const float* __restrict__ pks,
                          short* __restrict__ kv_b, short* __restrict__ ksum_b)
{
  const int idx = blockIdx.x * 256 + threadIdx.x;   // head*4096 + m*64 + d
  const int head = idx >> 12, md = idx & 4095;
  float s = 0.f;
  for (int i = 0; i < CH; ++i) s += pkv[((size_t)head * CH + i) * 4096 + md];
  kv_b[idx] = f2bf(s);
  if (md < 64) {
    float t = 0.f;
    for (int i = 0; i < CH; ++i) t += pks[((size_t)head * CH + i) * 64 + md];
    ksum_b[head * 64 + md] = f2bf(t + 1e-6f);
  }
}

// ---------------- fused attn + output GEMM (128 rows / 512 threads, r15-proven) ----------------
__global__ __launch_bounds__(512, 2)
void attn_out(const short* __restrict__ q_b, const short* __restrict__ kv_b,
              const short* __restrict__ ksum_b, const short* __restrict__ wo_t,
              const float* __restrict__ b_out, float* __restrict__ out)
{
  __shared__ __align__(16) char lds[81920];   // At 16KB @0 | Ws 64KB @16384
  const int tid = threadIdx.x;
  const int wv = tid >> 6, lane = tid & 63;
  const int fr = lane & 15, fq = lane >> 4;
  const int l0 = blockIdx.x * 128;
  const int bb = l0 >> 13;                    // batch index

  const int srow = tid >> 3;                  // 0..63
  const int sunit = (tid & 7) ^ (srow & 7);
  const short* Wg = wo_t + (size_t)srow * 512 + sunit * 8;
  char* ldsw = lds + 16384 + wv * 1024;       // + lane*16 implicit in gload_lds

  f32x4 acc[4][8] = {};

  for (int h = 0; h < 8; ++h) {
#pragma unroll
    for (int i = 0; i < 8; ++i)
      gload16(Wg + (size_t)(i * 64) * 512 + h * 64, ldsw + i * 8192);

    // ---- phase A: attn for head h, this wave's 16-row slab ----
    {
      const int hb = bb * 8 + h;
      const short* kvp = kv_b + (size_t)hb * 4096;
      const short* ksp = ksum_b + hb * 64;
      const short* qb = q_b + (size_t)(l0 + wv * 16) * 512 + h * 64;
      f32x4 accn[4] = {};
      f32x4 accd = {};
#pragma unroll
      for (int kk = 0; kk < 2; ++kk) {
        s16x8 a = *(const s16x8*)(qb + (size_t)fr * 512 + kk * 32 + fq * 8);
        s16x8 bden = *(const s16x8*)(ksp + kk * 32 + fq * 8);
        accd = __builtin_amdgcn_mfma_f32_16x16x32_bf16(a, bden, accd, 0, 0, 0);
#pragma unroll
        for (int j = 0; j < 4; ++j) {
          s16x8 bfr = *(const s16x8*)(kvp + (j * 16 + fr) * 64 + kk * 32 + fq * 8);
          accn[j] = __builtin_amdgcn_mfma_f32_16x16x32_bf16(a, bfr, accn[j], 0, 0, 0);
        }
      }
#pragma unroll
      for (int r = 0; r < 4; ++r) {
        const int row = wv * 16 + fq * 4 + r;
        const float dinv = 1.0f / accd[r];
#pragma unroll
        for (int j = 0; j < 4; ++j) {
          const int col = j * 16 + fr;
          *(short*)(lds + row * 128 + (((col >> 3) ^ (row & 7)) << 4) + ((col & 7) << 1))
              = f2bf(accn[j][r] * dinv);
        }
      }
    }
    __syncthreads();   // At ready + Ws landed

    // ---- phase B: wave tile 64x128, acc += At @ Ws^T over K=64 ----
    const int wm2 = wv >> 2, wn2 = wv & 3;
#pragma unroll
    for (int kk = 0; kk < 2; ++kk) {
      s16x8 af[4];
#pragma unroll
      for (int i = 0; i < 4; ++i) {
        const int row = wm2 * 64 + i * 16 + fr;
        const int u = (kk * 4 + fq) ^ (row & 7);
        af[i] = *(const s16x8*)(lds + row * 128 + u * 16);
      }
#pragma unroll
      for (int j = 0; j < 8; ++j) {
        const int n = wn2 * 128 + j * 16 + fr;
        const int u = (kk * 4 + fq) ^ (n & 7);
        s16x8 bw = *(const s16x8*)(lds + 16384 + n * 128 + u * 16);
#pragma unroll
        for (int i = 0; i < 4; ++i)
          acc[i][j] = __builtin_amdgcn_mfma_f32_16x16x32_bf16(af[i], bw, acc[i][j], 0, 0, 0);
      }
    }
    __syncthreads();   // protect At/Ws for next chunk
  }

  // ---- epilogue: 4 passes of 32 rows through 64KB fp32 scratch ----
  const int wm2 = wv >> 2, wn2 = wv & 3;
  float* scrf = (float*)lds;
#pragma unroll
  for (int p = 0; p < 4; ++p) {
    if (wm2 == (p >> 1)) {
#pragma unroll
      for (int ii = 0; ii < 2; ++ii) {
        const int i = (p & 1) * 2 + ii;
#pragma unroll
        for (int j = 0; j < 8; ++j) {
          const int col = wn2 * 128 + j * 16 + fr;
          const float bv = b_out[col];
#pragma unroll
          for (int r = 0; r < 4; ++r)
            scrf[(ii * 16 + fq * 4 + r) * 512 + col] = acc[i][j][r] + bv;
        }
      }
    }
    __syncthreads();
#pragma unroll
    for (int pp = 0; pp < 8; ++pp) {
      const int off = pp * 8192 + tid * 16;
      const int row = off >> 11, colb = off & 2047;   // 2KB per row (512 fp32)
      float4 v = *(const float4*)(lds + off);
      *(float4*)(out + (size_t)(l0 + p * 32 + row) * 512 + (colb >> 2)) = v;
    }
    __syncthreads();
  }
}

// ---------------- launch ----------------
extern "C" void kernel_launch(void* const* d_in, const int* in_sizes, int n_in,
                              void* d_out, int out_size, void* d_ws, size_t ws_size,
                              hipStream_t stream)
{
  const float* x     = (const float*)d_in[0];
  const float* w_qkv = (const float*)d_in[1];
  const float* b_qkv = (const float*)d_in[2];
  const float* w_out = (const float*)d_in[3];
  const float* b_out = (const float*)d_in[4];

  char* ws = (char*)d_ws;
  size_t off = 0;
  short* x_b   = (short*)(ws + off); off += (size_t)MM * DD * 2;        // 32 MB
  short* wq_t  = (short*)(ws + off); off += (size_t)NQKV * DD * 2;      // 1.5 MB
  short* wo_t  = (short*)(ws + off); off += (size_t)DD * DD * 2;        // 0.5 MB
  short* q_b   = (short*)(ws + off); off += (size_t)MM * DD * 2;        // 32 MB
  short* kt    = (short*)(ws + off); off += (size_t)32 * 64 * LL * 2;   // 32 MB
  short* vt    = (short*)(ws + off); off += (size_t)32 * 64 * LL * 2;   // 32 MB
  float* pkv   = (float*)(ws + off); off += (size_t)32 * CH * 4096 * 4; // 8 MB
  float* pks   = (float*)(ws + off); off += (size_t)32 * CH * 64 * 4;   // 0.13 MB
  short* kv_b  = (short*)(ws + off); off += (size_t)32 * 4096 * 2;      // 0.25 MB
  short* ksum_b= (short*)(ws + off); off += (size_t)32 * 64 * 2;        // 4 KB

  // fused conversions: x -> bf16 (8192 blocks), weight transposes via LDS tiles
  conv_all<<<dim3(9216), dim3(256), 0, stream>>>(x, w_qkv, w_out, x_b, wq_t, wo_t);

  // qkv GEMM: q -> q_b (phi), k -> kt (phi, transposed), v -> vt (transposed)
  gemm_bt<<<dim3(MM / 256, NQKV / 128), dim3(512), 0, stream>>>(
      x_b, wq_t, b_qkv, (void*)q_b, kt, vt);

  kv_mfma<<<dim3(32, CH), dim3(256), 0, stream>>>(kt, vt, pkv, pks);
  kv_reduce<<<dim3(512), dim3(256), 0, stream>>>(pkv, pks, kv_b, ksum_b);

  // fused attn + output GEMM -> d_out
  attn_out<<<dim3(MM / 128), dim3(512), 0, stream>>>(
      q_b, kv_b, ksum_b, wo_t, b_out, (float*)d_out);
}